// Round 3
// baseline (160.179 us; speedup 1.0000x reference)
//
#include <hip/hip_runtime.h>

// Problem constants (RefinementLayer1): B=2, L=192, D=768, NC=4, H=256
#define LSEQ 192
#define DIM  768
#define NCASE 4
#define HID  256
#define BATCH 2

// tanh(x) = 1 - 2/(exp2(K*x)+1), K = 2*log2(e). K folded into Bpack so the
// refine epilogue's tanh input (acc = K*mid) needs no extra scale.
#define TANH_K 2.885390081777927f

typedef float  floatx4 __attribute__((ext_vector_type(4)));
typedef float  floatx2 __attribute__((ext_vector_type(2)));
typedef __bf16 bf16x8  __attribute__((ext_vector_type(8)));
typedef __bf16 bf16x4  __attribute__((ext_vector_type(4)));

__device__ __forceinline__ float tanh_pre(float x) {   // x already * TANH_K
    float e = __builtin_amdgcn_exp2f(x);
    return 1.0f - 2.0f * __builtin_amdgcn_rcpf(e + 1.0f);
}

// ---- packed fp32 pairs: NATIVE vector ops (backend selects v_pk_*_f32
// with correct op_sel_hi; R13's hand asm got that wrong).
__device__ __forceinline__ floatx2 pk_fma2(floatx2 a, floatx2 b, floatx2 c) {
    return __builtin_elementwise_fma(a, b, c);
}
__device__ __forceinline__ floatx2 pk_add2(floatx2 a, floatx2 b) { return a + b; }
__device__ __forceinline__ floatx2 pk_mul2(floatx2 a, floatx2 b) { return a * b; }

// tanh(u+v) = (tu+tv)/(1+tu*tv) from tu=tanh(u), tv=tanh(v).
// 8 elements: 4 pk_fma + 4 pk_add + 8 rcp + 4 pk_mul (vs 32 scalar ops).
__device__ __forceinline__ bf16x8 tanh_add8(floatx4 u0, floatx4 u1,
                                            floatx4 v0, floatx4 v1) {
    const floatx2 one = {1.0f, 1.0f};
    float uu[8] = {u0[0], u0[1], u0[2], u0[3], u1[0], u1[1], u1[2], u1[3]};
    float vv[8] = {v0[0], v0[1], v0[2], v0[3], v1[0], v1[1], v1[2], v1[3]};
    bf16x8 r;
    #pragma unroll
    for (int i = 0; i < 4; i++) {
        floatx2 tu = {uu[2 * i], uu[2 * i + 1]};
        floatx2 tv = {vv[2 * i], vv[2 * i + 1]};
        floatx2 den = pk_fma2(tu, tv, one);
        floatx2 num = pk_add2(tu, tv);
        floatx2 rc;
        rc[0] = __builtin_amdgcn_rcpf(den[0]);
        rc[1] = __builtin_amdgcn_rcpf(den[1]);
        floatx2 res = pk_mul2(num, rc);
        r[2 * i]     = (__bf16)res[0];
        r[2 * i + 1] = (__bf16)res[1];
    }
    return r;
}

// Workgroup barrier draining ONLY lgkmcnt (LDS); global prefetches stay in
// flight. 0xC07F = vmcnt(63) expcnt(7) lgkmcnt(0).
__device__ __forceinline__ void barrier_lds_only() {
    __builtin_amdgcn_sched_barrier(0);
    __builtin_amdgcn_s_waitcnt(0xC07F);
    __builtin_amdgcn_s_barrier();
    __builtin_amdgcn_sched_barrier(0);
}

template <int CTRL>
__device__ __forceinline__ float dpp_add(float v) {
    int x = __builtin_amdgcn_update_dpp(0, __builtin_bit_cast(int, v),
                                        CTRL, 0xF, 0xF, true);
    return v + __builtin_bit_cast(float, x);
}
__device__ __forceinline__ float row16_reduce(float v) {
    v = dpp_add<0xB1>(v);    // quad_perm xor1
    v = dpp_add<0x4E>(v);    // quad_perm xor2
    v = dpp_add<0x141>(v);   // row_half_mirror
    v = dpp_add<0x140>(v);   // row_mirror
    return v;
}

// ---------------------------------------------------------------------------
// MFMA fragment layouts (m89/m91-verified, 16x16x32 bf16):
//   A: lane holds A[m = lane&15][k = (lane>>4)*8 + j]   (bf16x8)
//   B: lane holds B[k = (lane>>4)*8 + j][h = lane&15]   (bf16x8)
//   C/D: lane reg holds D[row = (lane>>4)*4 + reg][col = lane&15]
// ---------------------------------------------------------------------------

// ---------------------------------------------------------------------------
// Kernel 1 "prep" (unchanged — proven not the bottleneck).
// ---------------------------------------------------------------------------
__global__ __launch_bounds__(256) void prep(
    const float* __restrict__ seq, const float* __restrict__ Wp,
    const float* __restrict__ Wa,  const float* __restrict__ bp,
    const float* __restrict__ ba,  const float* __restrict__ Wmid,
    const float* __restrict__ bmid,
    float* __restrict__ lin, bf16x8* __restrict__ Bpack)
{
    const int blk = blockIdx.x;
    const int tid = threadIdx.x;

    if (blk >= 1920) {                     // ---- pack job
        int u = (blk - 1920) * 256 + tid;  // 0..36863 (one bf16x8 each)
        int lane = u & 63, f = u >> 6;
        int ct = f & 15, nk = f >> 4;      // nk = n*9 + kc
        int kc = nk % 9, n = nk / 9;
        int h = ct * 16 + (lane & 15);
        int kbase = kc * 32 + ((lane >> 4) & 3) * 8;
        bf16x8 v;
        #pragma unroll
        for (int j = 0; j < 8; j++) {
            int k = kbase + j;
            float x;
            if (k < 260)       x = Wmid[(size_t)(n * 260 + k) * 256 + h];
            else if (k == 260) x = bmid[n * 256 + h];
            else               x = 0.0f;
            v[j] = (__bf16)(TANH_K * x);
        }
        Bpack[u] = v;
        return;
    }

    // ---- lin unit: rt = blk/80, cg = blk%80; wave w = K-quarter
    const int w = tid >> 6, lane = tid & 63;
    const int rt = blk / 80, cg = blk % 80;
    const int quad  = lane >> 4;
    const int col16 = lane & 15;

    __shared__ float cmb[3][256];          // waves 1..3 partials, 3 KB

    const int arow = rt * 16 + col16;          // A: m = lane&15
    const int col  = cg * 16 + col16;          // output col 0..1279
    const int kofs = w * 192;
    const float* aptr = seq + (size_t)arow * DIM + kofs + quad * 8;
    const float* wbase = (cg < 16) ? (Wp + col) : (Wa + (col - 256));
    const int    wstr  = (cg < 16) ? HID : (NCASE * HID);

    floatx4 acc = {};
    floatx4 a0 = *(const floatx4*)(aptr);
    floatx4 a1 = *(const floatx4*)(aptr + 4);
    float bv[8];
    #pragma unroll
    for (int j = 0; j < 8; j++)
        bv[j] = wbase[(size_t)(kofs + quad * 8 + j) * wstr];

    #pragma unroll
    for (int kc = 0; kc < 6; kc++) {
        bf16x8 ah, al, bh, bl;
        #pragma unroll
        for (int j = 0; j < 4; j++) {
            __bf16 h0 = (__bf16)a0[j];
            ah[j] = h0; al[j] = (__bf16)(a0[j] - (float)h0);
            __bf16 h1 = (__bf16)a1[j];
            ah[4 + j] = h1; al[4 + j] = (__bf16)(a1[j] - (float)h1);
        }
        #pragma unroll
        for (int j = 0; j < 8; j++) {
            __bf16 h = (__bf16)bv[j];
            bh[j] = h; bl[j] = (__bf16)(bv[j] - (float)h);
        }
        if (kc < 5) {                      // prefetch next chunk
            a0 = *(const floatx4*)(aptr + (kc + 1) * 32);
            a1 = *(const floatx4*)(aptr + (kc + 1) * 32 + 4);
            #pragma unroll
            for (int j = 0; j < 8; j++)
                bv[j] = wbase[(size_t)(kofs + (kc + 1) * 32 + quad * 8 + j) * wstr];
        }
        acc = __builtin_amdgcn_mfma_f32_16x16x32_bf16(ah, bh, acc, 0, 0, 0);
        acc = __builtin_amdgcn_mfma_f32_16x16x32_bf16(al, bh, acc, 0, 0, 0);
        acc = __builtin_amdgcn_mfma_f32_16x16x32_bf16(ah, bl, acc, 0, 0, 0);
    }

    if (w > 0) *(floatx4*)&cmb[w - 1][lane * 4] = acc;
    __syncthreads();
    if (w == 0) {
        #pragma unroll
        for (int i = 0; i < 3; i++) {
            floatx4 p = *(const floatx4*)&cmb[i][lane * 4];
            acc += p;
        }
        const float bias = (cg < 16) ? bp[col] : ba[col - 256];
        #pragma unroll
        for (int reg = 0; reg < 4; reg++)
            lin[(size_t)(rt * 16 + quad * 4 + reg) * 1280 + col] =
                tanh_pre(TANH_K * (acc[reg] + bias));     // pre-activated
    }
}

// ---------------------------------------------------------------------------
// Kernel 2: fused main — R15 = R14 structure with the register bill cut so
// 3 blocks/CU come back (R14's regression driver: 8 live B-frags = 32 VGPR
// pushed unified regs past the 85 boundary -> 2 blocks/CU, occupancy 52->38).
//  (1) 2-chunk barrier phases: 5 barriers (kept from R14).
//  (2) packed fp32 tanh math via native floatx2 (kept).
//  (3) ROLLING per-chunk B prefetch: beven/bodd (16 regs max live).
//      bodd issued at phase start, consumed after gen+MFMA group 0 (~covers
//      L2 latency). Next beven issued mid-phase, rides across the lgkm-only
//      barrier (vmcnt NOT drained). p=3's next-even load IS folded chunk 8.
//  (4) wo[] load moved to epilogue (-2 live regs in the loop).
//  (5) __launch_bounds__(512, 6): force allocator <= ~80 unified regs.
// ---------------------------------------------------------------------------
__global__ __launch_bounds__(512, 6) void refine_main(
    const float* __restrict__ lin,        // [384][1280], PRE-TANH'd
    const float* __restrict__ base_score, // [B][L][NC][L]
    const float* __restrict__ Wout,       // [NC][256]
    const bf16x8* __restrict__ Bpack,     // packed Wmid frags (K-scaled)
    float* __restrict__ out)              // [B][L][NC][L]
{
    const int bx = blockIdx.x;            // 576 = 24*24
    const int n  = blockIdx.y;
    const int b  = blockIdx.z;
    const int ptile = bx / 24, atile = bx % 24;
    const int p0 = ptile * 8, a0r = atile * 8;

    const int tid   = threadIdx.x;
    const int w     = tid >> 6;           // wave 0..7, owns ct = w*2, w*2+1
    const int lane  = tid & 63;
    const int quad  = lane >> 4;
    const int col16 = lane & 15;

    __shared__ __align__(16) __bf16 Abuf[2][4096];   // 2 x (2 chunks) = 16 KB
    __shared__ float red[8][64];

    // A-gen slot: thread owns ONE slot s of chunk (2p+2 + chunk_off).
    const int chunk_off = tid >> 8;       // waves 0-3: even chunk, 4-7: odd
    const int s     = tid & 255;
    const int m_gen = ((s >> 6) << 4) + (s & 15);
    const int kq0   = ((s >> 4) & 3) * 8;

    const int pg = p0 + (m_gen >> 3), ag = a0r + (m_gen & 7);
    const float* hp_b = lin + (size_t)(b * LSEQ + pg) * 1280 + chunk_off * 32 + kq0;
    const float* ha_b = lin + (size_t)(b * LSEQ + ag) * 1280 + 256 + n * 256
                        + chunk_off * 32 + kq0;

    // B frags for wave w: index ((n*9 + kc)*16 + w*2 + ct)*64 + lane
    const bf16x8* bptr = Bpack + ((size_t)(n * 9) * 16 + w * 2) * 64 + lane;

    // chunk c lands in Abuf[(c>>1)&1], half (c&1) == chunk_off (invariant)
    __bf16* wptr = &Abuf[0][chunk_off * 2048 + s * 8];

    // ---- prologue
    float bs4[4] = {};
    if (chunk_off == 0 && kq0 == 0) {
        #pragma unroll
        for (int j = 0; j < 4; j++)
            bs4[j] = base_score[((size_t)(b * LSEQ + pg) * NCASE + j) * LSEQ + ag];
    }

    bf16x8 beven[2], bodd[2];
    #pragma unroll
    for (int ct = 0; ct < 2; ct++) beven[ct] = bptr[ct * 64];   // chunk 0

    floatx4 u0 = *(const floatx4*)(hp_b);
    floatx4 u1 = *(const floatx4*)(hp_b + 4);
    floatx4 v0 = *(const floatx4*)(ha_b);
    floatx4 v1 = *(const floatx4*)(ha_b + 4);
    *(bf16x8*)wptr = tanh_add8(u0, u1, v0, v1);      // chunks 0,1 -> Abuf[0]
    u0 = *(const floatx4*)(hp_b + 64);               // inputs for chunks 2,3
    u1 = *(const floatx4*)(hp_b + 68);
    v0 = *(const floatx4*)(ha_b + 64);
    v1 = *(const floatx4*)(ha_b + 68);
    barrier_lds_only();

    floatx4 acc[4][2] = {};   // [rt][ct]

    #pragma unroll
    for (int p = 0; p < 4; p++) {
        // odd-chunk B frags (chunk 2p+1): issued now, used after MFMA group 0
        #pragma unroll
        for (int ct = 0; ct < 2; ct++)
            bodd[ct] = bptr[((2 * p + 1) * 16 + ct) * 64];

        // generate chunk 2p+2+chunk_off into Abuf[(p+1)&1] (or folded chunk 8)
        __bf16* wp = wptr + (((p + 1) & 1) ? 4096 : 0);
        if (p < 3) {
            *(bf16x8*)wp = tanh_add8(u0, u1, v0, v1);
            if (p < 2) {                  // inputs for chunk 2p+4+chunk_off
                u0 = *(const floatx4*)(hp_b + (2 * p + 4) * 32);
                u1 = *(const floatx4*)(hp_b + (2 * p + 4) * 32 + 4);
                v0 = *(const floatx4*)(ha_b + (2 * p + 4) * 32);
                v1 = *(const floatx4*)(ha_b + (2 * p + 4) * 32 + 4);
            }
        } else if (chunk_off == 0) {      // folded chunk: A = [bs(4), 1, 0...]
            bf16x8 av = {};
            if (kq0 == 0) {
                #pragma unroll
                for (int j = 0; j < 4; j++) av[j] = (__bf16)bs4[j];
                av[4] = (__bf16)1.0f;     // k = 260 pairs with bmid row
            }
            *(bf16x8*)wp = av;            // Abuf[0] half 0
        }

        // MFMA chunk 2p (even) from Abuf[p&1] half 0, beven
        {
            const __bf16* rb = &Abuf[p & 1][0];
            bf16x8 af[4];
            #pragma unroll
            for (int rt = 0; rt < 4; rt++)
                af[rt] = *(const bf16x8*)&rb[(rt * 64 + lane) * 8];
            #pragma unroll
            for (int rt = 0; rt < 4; rt++)
                #pragma unroll
                for (int ct = 0; ct < 2; ct++)
                    acc[rt][ct] = __builtin_amdgcn_mfma_f32_16x16x32_bf16(
                        af[rt], beven[ct], acc[rt][ct], 0, 0, 0);
        }

        // next phase's even-chunk B frags (chunk 2p+2; p=3 -> folded chunk 8).
        // Issued here, ride across the lgkm-only barrier.
        #pragma unroll
        for (int ct = 0; ct < 2; ct++)
            beven[ct] = bptr[((2 * p + 2) * 16 + ct) * 64];

        // MFMA chunk 2p+1 (odd) from Abuf[p&1] half 1, bodd
        {
            const __bf16* rb = &Abuf[p & 1][2048];
            bf16x8 af[4];
            #pragma unroll
            for (int rt = 0; rt < 4; rt++)
                af[rt] = *(const bf16x8*)&rb[(rt * 64 + lane) * 8];
            #pragma unroll
            for (int rt = 0; rt < 4; rt++)
                #pragma unroll
                for (int ct = 0; ct < 2; ct++)
                    acc[rt][ct] = __builtin_amdgcn_mfma_f32_16x16x32_bf16(
                        af[rt], bodd[ct], acc[rt][ct], 0, 0, 0);
        }
        barrier_lds_only();
    }

    // ---- phase 4: folded chunk 8 (Abuf[0] half 0, B frags in beven)
    {
        const __bf16* rb = &Abuf[0][0];
        bf16x8 af[4];
        #pragma unroll
        for (int rt = 0; rt < 4; rt++)
            af[rt] = *(const bf16x8*)&rb[(rt * 64 + lane) * 8];
        #pragma unroll
        for (int rt = 0; rt < 4; rt++)
            #pragma unroll
            for (int ct = 0; ct < 2; ct++)
                acc[rt][ct] = __builtin_amdgcn_mfma_f32_16x16x32_bf16(
                    af[rt], beven[ct], acc[rt][ct], 0, 0, 0);
    }

    // ---- epilogue: tanh(acc) . Wout (acc = K*mid), packed fp32 math,
    //      DPP row reduce, cross-wave LDS combine
    float wo[2];
    #pragma unroll
    for (int ct = 0; ct < 2; ct++)
        wo[ct] = Wout[n * 256 + w * 32 + ct * 16 + col16];

    const floatx2 onex2 = {1.0f, 1.0f};
    const floatx2 m2x2  = {-2.0f, -2.0f};
    #pragma unroll
    for (int rt = 0; rt < 4; rt++) {
        #pragma unroll
        for (int reg = 0; reg < 4; reg++) {
            floatx2 e;
            e[0] = __builtin_amdgcn_exp2f(acc[rt][0][reg]);
            e[1] = __builtin_amdgcn_exp2f(acc[rt][1][reg]);
            floatx2 d = pk_add2(e, onex2);
            floatx2 rc;
            rc[0] = __builtin_amdgcn_rcpf(d[0]);
            rc[1] = __builtin_amdgcn_rcpf(d[1]);
            floatx2 th = pk_fma2(rc, m2x2, onex2);   // tanh = 1 - 2*rc
            float rs = __builtin_fmaf(th[1], wo[1], th[0] * wo[0]);
            rs = row16_reduce(rs);
            if (col16 == 0) red[w][rt * 16 + quad * 4 + reg] = rs;
        }
    }
    barrier_lds_only();

    if (tid < 64) {
        float total = red[0][tid] + red[1][tid] + red[2][tid] + red[3][tid]
                    + red[4][tid] + red[5][tid] + red[6][tid] + red[7][tid];
        const int p = p0 + (tid >> 3), a = a0r + (tid & 7);
        out[((size_t)(b * LSEQ + p) * NCASE + n) * LSEQ + a] = total;
    }
}

// ---------------------------------------------------------------------------
extern "C" void kernel_launch(void* const* d_in, const int* in_sizes, int n_in,
                              void* d_out, int out_size, void* d_ws, size_t ws_size,
                              hipStream_t stream) {
    const float* seq  = (const float*)d_in[0];
    const float* bsc  = (const float*)d_in[1];
    const float* Wp   = (const float*)d_in[2];
    const float* bp   = (const float*)d_in[3];
    const float* Wa   = (const float*)d_in[4];
    const float* ba   = (const float*)d_in[5];
    const float* Wmid = (const float*)d_in[6];
    const float* bmid = (const float*)d_in[7];
    const float* Wout = (const float*)d_in[8];
    float* out = (float*)d_out;

    char* ws = (char*)d_ws;
    float*  lin   = (float*)(ws);                      // 1,966,080 B
    bf16x8* Bpack = (bf16x8*)(ws + 1966080);           //   589,824 B

    prep<<<2064, 256, 0, stream>>>(seq, Wp, Wa, bp, ba, Wmid, bmid, lin, Bpack);
    refine_main<<<dim3(576, NCASE, BATCH), 512, 0, stream>>>(
        lin, bsc, Wout, Bpack, out);
}

// Round 4
// 149.606 us; speedup vs baseline: 1.0707x; 1.0707x over previous
//
#include <hip/hip_runtime.h>

// Problem constants (RefinementLayer1): B=2, L=192, D=768, NC=4, H=256
#define LSEQ 192
#define DIM  768
#define NCASE 4
#define HID  256
#define BATCH 2

// tanh(x) = 1 - 2/(exp2(K*x)+1), K = 2*log2(e). K folded into Bpack so the
// refine epilogue's tanh input (acc = K*mid) needs no extra scale.
#define TANH_K 2.885390081777927f

typedef float  floatx4 __attribute__((ext_vector_type(4)));
typedef float  floatx2 __attribute__((ext_vector_type(2)));
typedef __bf16 bf16x8  __attribute__((ext_vector_type(8)));
typedef __bf16 bf16x4  __attribute__((ext_vector_type(4)));

__device__ __forceinline__ float tanh_pre(float x) {   // x already * TANH_K
    float e = __builtin_amdgcn_exp2f(x);
    return 1.0f - 2.0f * __builtin_amdgcn_rcpf(e + 1.0f);
}

// ---- packed fp32 pairs: NATIVE vector ops (backend selects v_pk_*_f32 with
// correct op_sel_hi; validated in R14/R15 passes).
__device__ __forceinline__ floatx2 pk_fma2(floatx2 a, floatx2 b, floatx2 c) {
    return __builtin_elementwise_fma(a, b, c);
}
__device__ __forceinline__ floatx2 pk_add2(floatx2 a, floatx2 b) { return a + b; }
__device__ __forceinline__ floatx2 pk_mul2(floatx2 a, floatx2 b) { return a * b; }

// tanh(u+v) = (tu+tv)/(1+tu*tv) from tu=tanh(u), tv=tanh(v).
// 4 elements packed: 2 pk_fma + 2 pk_add + 4 rcp + 2 pk_mul.
__device__ __forceinline__ bf16x4 tanh_add4(floatx4 u, floatx4 v) {
    const floatx2 one = {1.0f, 1.0f};
    bf16x4 r;
    #pragma unroll
    for (int i = 0; i < 2; i++) {
        floatx2 tu = {u[2 * i], u[2 * i + 1]};
        floatx2 tv = {v[2 * i], v[2 * i + 1]};
        floatx2 den = pk_fma2(tu, tv, one);
        floatx2 num = pk_add2(tu, tv);
        floatx2 rc;
        rc[0] = __builtin_amdgcn_rcpf(den[0]);
        rc[1] = __builtin_amdgcn_rcpf(den[1]);
        floatx2 res = pk_mul2(num, rc);
        r[2 * i]     = (__bf16)res[0];
        r[2 * i + 1] = (__bf16)res[1];
    }
    return r;
}

// Workgroup barrier draining ONLY lgkmcnt (LDS); global prefetches stay in
// flight. 0xC07F = vmcnt(63) expcnt(7) lgkmcnt(0).
__device__ __forceinline__ void barrier_lds_only() {
    __builtin_amdgcn_sched_barrier(0);
    __builtin_amdgcn_s_waitcnt(0xC07F);
    __builtin_amdgcn_s_barrier();
    __builtin_amdgcn_sched_barrier(0);
}

template <int CTRL>
__device__ __forceinline__ float dpp_add(float v) {
    int x = __builtin_amdgcn_update_dpp(0, __builtin_bit_cast(int, v),
                                        CTRL, 0xF, 0xF, true);
    return v + __builtin_bit_cast(float, x);
}
__device__ __forceinline__ float row16_reduce(float v) {
    v = dpp_add<0xB1>(v);    // quad_perm xor1
    v = dpp_add<0x4E>(v);    // quad_perm xor2
    v = dpp_add<0x141>(v);   // row_half_mirror
    v = dpp_add<0x140>(v);   // row_mirror
    return v;
}

// ---------------------------------------------------------------------------
// MFMA fragment layouts (m89/m91-verified, 16x16x32 bf16):
//   A: lane holds A[m = lane&15][k = (lane>>4)*8 + j]   (bf16x8)
//   B: lane holds B[k = (lane>>4)*8 + j][h = lane&15]   (bf16x8)
//   C/D: lane reg holds D[row = (lane>>4)*4 + reg][col = lane&15]
// ---------------------------------------------------------------------------

// ---------------------------------------------------------------------------
// Kernel 1 "prep" (unchanged — proven not the bottleneck).
// ---------------------------------------------------------------------------
__global__ __launch_bounds__(256) void prep(
    const float* __restrict__ seq, const float* __restrict__ Wp,
    const float* __restrict__ Wa,  const float* __restrict__ bp,
    const float* __restrict__ ba,  const float* __restrict__ Wmid,
    const float* __restrict__ bmid,
    float* __restrict__ lin, bf16x8* __restrict__ Bpack)
{
    const int blk = blockIdx.x;
    const int tid = threadIdx.x;

    if (blk >= 1920) {                     // ---- pack job
        int u = (blk - 1920) * 256 + tid;  // 0..36863 (one bf16x8 each)
        int lane = u & 63, f = u >> 6;
        int ct = f & 15, nk = f >> 4;      // nk = n*9 + kc
        int kc = nk % 9, n = nk / 9;
        int h = ct * 16 + (lane & 15);
        int kbase = kc * 32 + ((lane >> 4) & 3) * 8;
        bf16x8 v;
        #pragma unroll
        for (int j = 0; j < 8; j++) {
            int k = kbase + j;
            float x;
            if (k < 260)       x = Wmid[(size_t)(n * 260 + k) * 256 + h];
            else if (k == 260) x = bmid[n * 256 + h];
            else               x = 0.0f;
            v[j] = (__bf16)(TANH_K * x);
        }
        Bpack[u] = v;
        return;
    }

    // ---- lin unit: rt = blk/80, cg = blk%80; wave w = K-quarter
    const int w = tid >> 6, lane = tid & 63;
    const int rt = blk / 80, cg = blk % 80;
    const int quad  = lane >> 4;
    const int col16 = lane & 15;

    __shared__ float cmb[3][256];          // waves 1..3 partials, 3 KB

    const int arow = rt * 16 + col16;          // A: m = lane&15
    const int col  = cg * 16 + col16;          // output col 0..1279
    const int kofs = w * 192;
    const float* aptr = seq + (size_t)arow * DIM + kofs + quad * 8;
    const float* wbase = (cg < 16) ? (Wp + col) : (Wa + (col - 256));
    const int    wstr  = (cg < 16) ? HID : (NCASE * HID);

    floatx4 acc = {};
    floatx4 a0 = *(const floatx4*)(aptr);
    floatx4 a1 = *(const floatx4*)(aptr + 4);
    float bv[8];
    #pragma unroll
    for (int j = 0; j < 8; j++)
        bv[j] = wbase[(size_t)(kofs + quad * 8 + j) * wstr];

    #pragma unroll
    for (int kc = 0; kc < 6; kc++) {
        bf16x8 ah, al, bh, bl;
        #pragma unroll
        for (int j = 0; j < 4; j++) {
            __bf16 h0 = (__bf16)a0[j];
            ah[j] = h0; al[j] = (__bf16)(a0[j] - (float)h0);
            __bf16 h1 = (__bf16)a1[j];
            ah[4 + j] = h1; al[4 + j] = (__bf16)(a1[j] - (float)h1);
        }
        #pragma unroll
        for (int j = 0; j < 8; j++) {
            __bf16 h = (__bf16)bv[j];
            bh[j] = h; bl[j] = (__bf16)(bv[j] - (float)h);
        }
        if (kc < 5) {                      // prefetch next chunk
            a0 = *(const floatx4*)(aptr + (kc + 1) * 32);
            a1 = *(const floatx4*)(aptr + (kc + 1) * 32 + 4);
            #pragma unroll
            for (int j = 0; j < 8; j++)
                bv[j] = wbase[(size_t)(kofs + (kc + 1) * 32 + quad * 8 + j) * wstr];
        }
        acc = __builtin_amdgcn_mfma_f32_16x16x32_bf16(ah, bh, acc, 0, 0, 0);
        acc = __builtin_amdgcn_mfma_f32_16x16x32_bf16(al, bh, acc, 0, 0, 0);
        acc = __builtin_amdgcn_mfma_f32_16x16x32_bf16(ah, bl, acc, 0, 0, 0);
    }

    if (w > 0) *(floatx4*)&cmb[w - 1][lane * 4] = acc;
    __syncthreads();
    if (w == 0) {
        #pragma unroll
        for (int i = 0; i < 3; i++) {
            floatx4 p = *(const floatx4*)&cmb[i][lane * 4];
            acc += p;
        }
        const float bias = (cg < 16) ? bp[col] : ba[col - 256];
        #pragma unroll
        for (int reg = 0; reg < 4; reg++)
            lin[(size_t)(rt * 16 + quad * 4 + reg) * 1280 + col] =
                tanh_pre(TANH_K * (acc[reg] + bias));     // pre-activated
    }
}

// ---------------------------------------------------------------------------
// Kernel 2: fused main — R16: REVERT to the proven R12 loop structure
// (1-chunk phases, 9 barriers, half-slot A-gen, 4-frag B ping-pong — 73.6us
// measured; the R13-R15 2-chunk phase experiments were ~84us at BOTH 38% and
// 55% occupancy, isolating the structure itself as the regression). On top of
// the reverted loop, keep only the loop-exterior / arithmetic-identical parts
// of the VALU diet, both validated in R14/R15 passes:
//  (a) packed-fp32 epilogue (v_pk_* via native floatx2),
//  (b) packed 4-element gen (tanh_add4: 2 pk pairs + 4 rcp).
// ---------------------------------------------------------------------------
__global__ __launch_bounds__(512, 6) void refine_main(
    const float* __restrict__ lin,        // [384][1280], PRE-TANH'd
    const float* __restrict__ base_score, // [B][L][NC][L]
    const float* __restrict__ Wout,       // [NC][256]
    const bf16x8* __restrict__ Bpack,     // packed Wmid frags (K-scaled)
    float* __restrict__ out)              // [B][L][NC][L]
{
    const int bx = blockIdx.x;            // 576 = 24*24
    const int n  = blockIdx.y;
    const int b  = blockIdx.z;
    const int ptile = bx / 24, atile = bx % 24;
    const int p0 = ptile * 8, a0r = atile * 8;

    const int tid   = threadIdx.x;
    const int w     = tid >> 6;           // wave 0..7, owns ct = w*2, w*2+1
    const int lane  = tid & 63;
    const int quad  = lane >> 4;
    const int col16 = lane & 15;

    __shared__ __align__(16) __bf16 A0[256 * 8];   // 4 KB frag buf (even kc)
    __shared__ __align__(16) __bf16 A1[256 * 8];   // 4 KB frag buf (odd kc)
    __shared__ float red[8][64];

    // A-gen half-slot: slot s = tid>>1 (l = s&63), half = tid&1.
    const int s_g    = tid >> 1;
    const int h2     = tid & 1;
    const int l_g    = s_g & 63;
    const int m_gen  = ((s_g >> 6) << 4) + (l_g & 15);
    const int kq     = (l_g >> 4) * 8 + h2 * 4;
    const int quad_g = l_g >> 4;

    const int pg = p0 + (m_gen >> 3), ag = a0r + (m_gen & 7);
    const float* hp_ptr = lin + (size_t)(b * LSEQ + pg) * 1280 + kq;
    const float* ha_ptr = lin + (size_t)(b * LSEQ + ag) * 1280 + 256 + n * 256 + kq;

    // B frags for wave w: index ((n*9 + kc)*16 + w*2 + ct)*64 + lane
    const bf16x8* bbase = Bpack + ((size_t)(n * 9) * 16 + w * 2) * 64 + lane;

    // ---- prologue
    float bs4[4] = {};
    if (quad_g == 0 && h2 == 0) {
        #pragma unroll
        for (int j = 0; j < 4; j++)
            bs4[j] = base_score[((size_t)(b * LSEQ + pg) * NCASE + j) * LSEQ + ag];
    }
    float wo[2];
    #pragma unroll
    for (int ct = 0; ct < 2; ct++)
        wo[ct] = Wout[n * 256 + w * 32 + ct * 16 + col16];

    bf16x8 bcur[2];
    #pragma unroll
    for (int ct = 0; ct < 2; ct++) bcur[ct] = bbase[ct * 64];

    floatx4 hp = *(const floatx4*)(hp_ptr);
    floatx4 ha = *(const floatx4*)(ha_ptr);
    {   // av(0) -> A0 (half-slot)
        *(bf16x4*)&A0[tid * 4] = tanh_add4(hp, ha);
    }
    hp = *(const floatx4*)(hp_ptr + 32);   // chunk 1 inputs
    ha = *(const floatx4*)(ha_ptr + 32);
    barrier_lds_only();

    floatx4 acc[4][2] = {};   // [rt][ct]

    #pragma unroll
    for (int kc = 0; kc < 9; kc++) {
        // B prefetch for chunk kc+1 (stays in flight across the barrier)
        bf16x8 bnext[2];
        if (kc < 8) {
            #pragma unroll
            for (int ct = 0; ct < 2; ct++)
                bnext[ct] = bbase[((kc + 1) * 16 + ct) * 64];
        }
        // generate av(kc+1) into the other buffer (overlaps MFMA below)
        if (kc < 7) {
            floatx4 u0 = hp, v0 = ha;
            if (kc < 6) {                 // prefetch inputs for chunk kc+2
                hp = *(const floatx4*)(hp_ptr + (kc + 2) * 32);
                ha = *(const floatx4*)(ha_ptr + (kc + 2) * 32);
            }
            __bf16* buf = ((kc + 1) & 1) ? A1 : A0;
            *(bf16x4*)&buf[tid * 4] = tanh_add4(u0, v0);
        } else if (kc == 7) {             // folded chunk: A = [bs(4), 1, 0...]
            bf16x4 av = {};
            if (quad_g == 0) {
                if (h2 == 0) {
                    #pragma unroll
                    for (int j = 0; j < 4; j++) av[j] = (__bf16)bs4[j];
                } else {
                    av[0] = (__bf16)1.0f;  // k = 4 pairs with bmid row
                }
            }
            *(bf16x4*)&A0[tid * 4] = av;   // (7+1)&1 == 0
        }

        // MFMA(kc) from buf[kc&1]
        const __bf16* rb = (kc & 1) ? A1 : A0;
        bf16x8 af[4];
        #pragma unroll
        for (int rt = 0; rt < 4; rt++)
            af[rt] = *(const bf16x8*)&rb[(rt * 64 + lane) * 8];
        #pragma unroll
        for (int rt = 0; rt < 4; rt++)
            #pragma unroll
            for (int ct = 0; ct < 2; ct++)
                acc[rt][ct] = __builtin_amdgcn_mfma_f32_16x16x32_bf16(
                    af[rt], bcur[ct], acc[rt][ct], 0, 0, 0);
        #pragma unroll
        for (int ct = 0; ct < 2; ct++) bcur[ct] = bnext[ct];
        if (kc < 8) barrier_lds_only();
    }

    // ---- epilogue: tanh(acc) . Wout (acc = K*mid), packed fp32 math,
    //      DPP row reduce, cross-wave LDS combine
    const floatx2 onex2 = {1.0f, 1.0f};
    const floatx2 m2x2  = {-2.0f, -2.0f};
    #pragma unroll
    for (int rt = 0; rt < 4; rt++) {
        #pragma unroll
        for (int reg = 0; reg < 4; reg++) {
            floatx2 e;
            e[0] = __builtin_amdgcn_exp2f(acc[rt][0][reg]);
            e[1] = __builtin_amdgcn_exp2f(acc[rt][1][reg]);
            floatx2 d = pk_add2(e, onex2);
            floatx2 rc;
            rc[0] = __builtin_amdgcn_rcpf(d[0]);
            rc[1] = __builtin_amdgcn_rcpf(d[1]);
            floatx2 th = pk_fma2(rc, m2x2, onex2);   // tanh = 1 - 2*rc
            float rs = __builtin_fmaf(th[1], wo[1], th[0] * wo[0]);
            rs = row16_reduce(rs);
            if (col16 == 0) red[w][rt * 16 + quad * 4 + reg] = rs;
        }
    }
    barrier_lds_only();

    if (tid < 64) {
        float total = red[0][tid] + red[1][tid] + red[2][tid] + red[3][tid]
                    + red[4][tid] + red[5][tid] + red[6][tid] + red[7][tid];
        const int p = p0 + (tid >> 3), a = a0r + (tid & 7);
        out[((size_t)(b * LSEQ + p) * NCASE + n) * LSEQ + a] = total;
    }
}

// ---------------------------------------------------------------------------
extern "C" void kernel_launch(void* const* d_in, const int* in_sizes, int n_in,
                              void* d_out, int out_size, void* d_ws, size_t ws_size,
                              hipStream_t stream) {
    const float* seq  = (const float*)d_in[0];
    const float* bsc  = (const float*)d_in[1];
    const float* Wp   = (const float*)d_in[2];
    const float* bp   = (const float*)d_in[3];
    const float* Wa   = (const float*)d_in[4];
    const float* ba   = (const float*)d_in[5];
    const float* Wmid = (const float*)d_in[6];
    const float* bmid = (const float*)d_in[7];
    const float* Wout = (const float*)d_in[8];
    float* out = (float*)d_out;

    char* ws = (char*)d_ws;
    float*  lin   = (float*)(ws);                      // 1,966,080 B
    bf16x8* Bpack = (bf16x8*)(ws + 1966080);           //   589,824 B

    prep<<<2064, 256, 0, stream>>>(seq, Wp, Wa, bp, ba, Wmid, bmid, lin, Bpack);
    refine_main<<<dim3(576, NCASE, BATCH), 512, 0, stream>>>(
        lin, bsc, Wout, Bpack, out);
}